// Round 10
// baseline (222.132 us; speedup 1.0000x reference)
//
#include <hip/hip_runtime.h>
#include <hip/hip_fp16.h>

#define Bn  4
#define Hn  256
#define Wn  256
#define Cn  16
#define NTn 9
#define HWn (Hn*Wn)
#define KF  129      // W/2 + 1
#define KGP 136      // padded k-row length of G (17 octets)
#define PI_F 3.14159265358979323846f

__device__ __forceinline__ int swz(int i) { return i ^ ((i >> 4) & 15); }

__device__ __forceinline__ void lds_fence() {
  __asm__ volatile("s_waitcnt lgkmcnt(0)" ::: "memory");
}

__device__ __forceinline__ float2 cmul(float2 a, float2 b) {
  return make_float2(a.x*b.x - a.y*b.y, a.x*b.y + a.y*b.x);
}

template<bool INV>
__device__ __forceinline__ void radix4(float2& x0, float2& x1, float2& x2, float2& x3) {
  float2 y0 = make_float2(x0.x + x2.x, x0.y + x2.y);
  float2 y1 = make_float2(x0.x - x2.x, x0.y - x2.y);
  float2 y2 = make_float2(x1.x + x3.x, x1.y + x3.y);
  float2 y3 = make_float2(x1.x - x3.x, x1.y - x3.y);
  x0 = make_float2(y0.x + y2.x, y0.y + y2.y);
  x2 = make_float2(y0.x - y2.x, y0.y - y2.y);
  if (!INV) {
    x1 = make_float2(y1.x + y3.y, y1.y - y3.x);   // y1 - i*y3
    x3 = make_float2(y1.x - y3.y, y1.y + y3.x);   // y1 + i*y3
  } else {
    x1 = make_float2(y1.x - y3.y, y1.y + y3.x);
    x3 = make_float2(y1.x + y3.y, y1.y - y3.x);
  }
}

struct Tw { float2 a1,a2,a3,b1,b2,b3,c1,c2,c3; };

template<bool INV>
__device__ __forceinline__ Tw make_tw(int lane) {
  const float sgn = INV ? 2.0f * PI_F : -2.0f * PI_F;
  Tw t; float sw, cw;
  __sincosf(sgn * (float)lane / 256.0f, &sw, &cw);
  t.a1 = make_float2(cw, sw); t.a2 = cmul(t.a1, t.a1); t.a3 = cmul(t.a2, t.a1);
  __sincosf(sgn * (float)(lane & 15) / 64.0f, &sw, &cw);
  t.b1 = make_float2(cw, sw); t.b2 = cmul(t.b1, t.b1); t.b3 = cmul(t.b2, t.b1);
  __sincosf(sgn * (float)(lane & 3) / 16.0f, &sw, &cw);
  t.c1 = make_float2(cw, sw); t.c2 = cmul(t.c1, t.c1); t.c3 = cmul(t.c2, t.c1);
  return t;
}

// Per-wave FFT-256, radix-4 DIF. Input v[a]=x[lane+64a]; natural-order output
// in scratch row s (read via s[swz(k)]). Wave-private s, no __syncthreads.
template<bool INV>
__device__ __forceinline__ void fft256(float2 v[4], float2* s, int lane, const Tw& t) {
  radix4<INV>(v[0], v[1], v[2], v[3]);
  v[1] = cmul(v[1], t.a1); v[2] = cmul(v[2], t.a2); v[3] = cmul(v[3], t.a3);
  s[swz(lane)]       = v[0];
  s[swz(lane + 64)]  = v[1];
  s[swz(lane + 128)] = v[2];
  s[swz(lane + 192)] = v[3];
  lds_fence();
  { int base = (lane >> 4) * 64 + (lane & 15);
    v[0] = s[swz(base)]; v[1] = s[swz(base + 16)];
    v[2] = s[swz(base + 32)]; v[3] = s[swz(base + 48)]; }
  lds_fence();
  radix4<INV>(v[0], v[1], v[2], v[3]);
  v[1] = cmul(v[1], t.b1); v[2] = cmul(v[2], t.b2); v[3] = cmul(v[3], t.b3);
  { int base = (lane >> 4) * 64 + (lane & 15);
    s[swz(base)]      = v[0];
    s[swz(base + 16)] = v[1];
    s[swz(base + 32)] = v[2];
    s[swz(base + 48)] = v[3]; }
  lds_fence();
  { int base = (lane >> 4) * 64 + ((lane >> 2) & 3) * 16 + (lane & 3);
    v[0] = s[swz(base)]; v[1] = s[swz(base + 4)];
    v[2] = s[swz(base + 8)]; v[3] = s[swz(base + 12)]; }
  lds_fence();
  radix4<INV>(v[0], v[1], v[2], v[3]);
  v[1] = cmul(v[1], t.c1); v[2] = cmul(v[2], t.c2); v[3] = cmul(v[3], t.c3);
  { int base = (lane & ~3) * 4 + (lane & 3);
    s[swz(base)]      = v[0];
    s[swz(base + 4)]  = v[1];
    s[swz(base + 8)]  = v[2];
    s[swz(base + 12)] = v[3]; }
  lds_fence();
  { int base = lane * 4;
    v[0] = s[swz(base)]; v[1] = s[swz(base + 1)];
    v[2] = s[swz(base + 2)]; v[3] = s[swz(base + 3)]; }
  lds_fence();
  radix4<INV>(v[0], v[1], v[2], v[3]);
  int dr = ((lane & 3) << 4) + (((lane >> 2) & 3) << 2) + (lane >> 4);
  s[swz(dr)]       = v[0];
  s[swz(dr + 64)]  = v[1];
  s[swz(dr + 128)] = v[2];
  s[swz(dr + 192)] = v[3];
  lds_fence();
}

// Inline projective warp map (matches reference: fp-contract off, rintf).
__device__ __forceinline__ int warp_id(float a0, float a1, float a2, float a3,
                                       float a4, float a5, float a6, float a7,
                                       int col, int row) {
#pragma clang fp contract(off)
  float x = (float)col, y = (float)row;
  float kk = a6 * x + a7 * y + 1.0f;
  float xf = (a0 * x + a1 * y + a2) / kk;
  float yf = (a3 * x + a4 * y + a5) / kk;
  float xr = rintf(xf), yr = rintf(yf);
  bool valid = (xr >= 0.f) && (xr < 256.f) && (yr >= 0.f) && (yr < 256.f);
  return valid ? ((int)yr * Wn + (int)xr) : -1;
}

// ---------------------------------------------------------------------------
__global__ void k_zero(float* __restrict__ ny2) {
  int t = threadIdx.x;
  for (int i = t; i < NTn * Bn * Cn; i += 256) ny2[i] = 0.f;
}

// ---------------------------------------------------------------------------
// Row FFT of warped y (t=0 slab == x spectra, identity warp).
// Block = (cg HIGH bits, tb, 16-row chunk): cg in high bits (stride 576 ≡ 0
// mod 8) so the 4 cg-blocks sharing (tb,chunk) land on the SAME XCD and share
// the gathered 64B pixel lines in its L2. Real-pair row packing, inline warp
// map, fused ||y||^2.
// ---------------------------------------------------------------------------
__global__ __launch_bounds__(256) void k_yrow(const float* __restrict__ inp,
                                              const float* __restrict__ T,
                                              __half2* __restrict__ Yh,
                                              float* __restrict__ ny2) {
  __shared__ float   ych[2][4][264];
  __shared__ float2  sb[4][264];
  __shared__ __half2 specbuf[4][8][132];
  __shared__ float4  redw[4];
  int tid = threadIdx.x, w = tid >> 6, lane = tid & 63;
  Tw t = make_tw<false>(lane);
  int cg = blockIdx.x / 576;                 // high bits -> same XCD for quad
  int rest = blockIdx.x % 576;               // tb*16 + chunk
  int tb = rest >> 4, chunk = rest & 15;
  int b = tb & 3, tt = tb >> 2;
  int i0 = chunk << 4;
  const float4* ib = (const float4*)(inp + (size_t)b * HWn * Cn);
  float a0, a1, a2, a3, a4, a5, a6, a7;
  { const float* a = T + tt * 8;
    a0=a[0]; a1=a[1]; a2=a[2]; a3=a[3]; a4=a[4]; a5=a[5]; a6=a[6]; a7=a[7]; }
  float4 nyacc = make_float4(0.f, 0.f, 0.f, 0.f);
  float4 g0, g1;
  {
    int id0 = warp_id(a0,a1,a2,a3,a4,a5,a6,a7, tid, i0);
    int id1 = warp_id(a0,a1,a2,a3,a4,a5,a6,a7, tid, i0 + 1);
    g0 = (id0 >= 0) ? ib[(size_t)id0 * 4 + cg] : make_float4(0.f,0.f,0.f,0.f);
    g1 = (id1 >= 0) ? ib[(size_t)id1 * 4 + cg] : make_float4(0.f,0.f,0.f,0.f);
  }
  for (int pr = 0; pr < 8; ++pr) {
    if (pr == 4) {
      __syncthreads();
      int ii = tid & 7, kq = tid >> 3;
#pragma unroll
      for (int p = 0; p < 5; ++p) {
        int k = p * 32 + kq;
        if (k <= 128) {
#pragma unroll
          for (int cc = 0; cc < 4; ++cc)
            Yh[((size_t)(tb * Cn + cg * 4 + cc) * KF + k) * Hn + i0 + ii] = specbuf[cc][ii][k];
        }
      }
    }
    __syncthreads();
    ych[0][0][tid] = g0.x; ych[0][1][tid] = g0.y; ych[0][2][tid] = g0.z; ych[0][3][tid] = g0.w;
    ych[1][0][tid] = g1.x; ych[1][1][tid] = g1.y; ych[1][2][tid] = g1.z; ych[1][3][tid] = g1.w;
    nyacc.x += g0.x*g0.x + g1.x*g1.x; nyacc.y += g0.y*g0.y + g1.y*g1.y;
    nyacc.z += g0.z*g0.z + g1.z*g1.z; nyacc.w += g0.w*g0.w + g1.w*g1.w;
    __syncthreads();
    if (pr < 7) {
      int r0 = i0 + 2 * (pr + 1);
      int id0 = warp_id(a0,a1,a2,a3,a4,a5,a6,a7, tid, r0);
      int id1 = warp_id(a0,a1,a2,a3,a4,a5,a6,a7, tid, r0 + 1);
      g0 = (id0 >= 0) ? ib[(size_t)id0 * 4 + cg] : make_float4(0.f,0.f,0.f,0.f);
      g1 = (id1 >= 0) ? ib[(size_t)id1 * 4 + cg] : make_float4(0.f,0.f,0.f,0.f);
    }
    float2 v[4];
#pragma unroll
    for (int q = 0; q < 4; ++q) {
      int j = lane + (q << 6);
      v[q] = make_float2(ych[0][w][j], ych[1][w][j]);
    }
    fft256<false>(v, sb[w], lane, t);
    int lr0 = (2 * pr) & 7, lr1 = lr0 + 1;
#pragma unroll
    for (int q = 0; q < 2; ++q) {
      int k = lane + (q << 6);
      float2 Z  = sb[w][swz(k)];
      float2 Zc = sb[w][swz((256 - k) & 255)];
      float2 Fa = make_float2(0.5f * (Z.x + Zc.x), 0.5f * (Z.y - Zc.y));
      float2 Fb = make_float2(0.5f * (Z.y + Zc.y), 0.5f * (Zc.x - Z.x));
      specbuf[w][lr0][k] = __float22half2_rn(Fa);
      specbuf[w][lr1][k] = __float22half2_rn(Fb);
    }
    if (lane == 0) {
      float2 Z = sb[w][swz(128)];
      specbuf[w][lr0][128] = __float22half2_rn(make_float2(Z.x, 0.f));
      specbuf[w][lr1][128] = __float22half2_rn(make_float2(Z.y, 0.f));
    }
  }
#pragma unroll
  for (int o = 32; o > 0; o >>= 1) {
    nyacc.x += __shfl_down(nyacc.x, o, 64);
    nyacc.y += __shfl_down(nyacc.y, o, 64);
    nyacc.z += __shfl_down(nyacc.z, o, 64);
    nyacc.w += __shfl_down(nyacc.w, o, 64);
  }
  if (lane == 0) redw[w] = nyacc;
  __syncthreads();
  {
    int ii = tid & 7, kq = tid >> 3;
#pragma unroll
    for (int p = 0; p < 5; ++p) {
      int k = p * 32 + kq;
      if (k <= 128) {
#pragma unroll
        for (int cc = 0; cc < 4; ++cc)
          Yh[((size_t)(tb * Cn + cg * 4 + cc) * KF + k) * Hn + i0 + 8 + ii] = specbuf[cc][ii][k];
      }
    }
  }
  if (tid == 0) {
    float4 s = make_float4(redw[0].x + redw[1].x + redw[2].x + redw[3].x,
                           redw[0].y + redw[1].y + redw[2].y + redw[3].y,
                           redw[0].z + redw[1].z + redw[2].z + redw[3].z,
                           redw[0].w + redw[1].w + redw[2].w + redw[3].w);
    atomicAdd(ny2 + tb * Cn + cg * 4 + 0, s.x);
    atomicAdd(ny2 + tb * Cn + cg * 4 + 1, s.y);
    atomicAdd(ny2 + tb * Cn + cg * 4 + 2, s.z);
    atomicAdd(ny2 + tb * Cn + cg * 4 + 3, s.w);
  }
}

// ---------------------------------------------------------------------------
// Column FFT of x spectra: reads t=0 slab of Yh (contiguous), writes Fxh
// (contiguous). Wave per item, no barriers.
// ---------------------------------------------------------------------------
__global__ void k_colfft_fx(const __half2* __restrict__ Yh, __half2* __restrict__ Fxh) {
  __shared__ float2 sb[4][264];
  int w = threadIdx.x >> 6, lane = threadIdx.x & 63;
  Tw t = make_tw<false>(lane);
  int item = blockIdx.x * 4 + w;            // (b*16+c)*KF + k
  const __half2* Sp = Yh + (size_t)item * Hn;
  float2 v[4];
#pragma unroll
  for (int q = 0; q < 4; ++q) v[q] = __half22float2(Sp[lane + (q << 6)]);
  fft256<false>(v, sb[w], lane, t);
  __half2* Op = Fxh + (size_t)item * Hn;
#pragma unroll
  for (int q = 0; q < 4; ++q) {
    int j = lane + (q << 6);
    Op[j] = __float22half2_rn(sb[w][swz(j)]);
  }
}

// ---------------------------------------------------------------------------
// Block = (tb, k-octet): 8 waves, wave w owns k = oct*8+w. Per wave (barrier-
// free): column FFT over 16 channels + Fx*conj(Fy)*scale accum + fused
// inverse FFT over row-frequency. Then ONE barrier and a cooperative 64B-
// granule transposed store into G[tb][j][k] (row padded to 136).
// ---------------------------------------------------------------------------
__global__ __launch_bounds__(512) void k_ycol(const __half2* __restrict__ Yh,
                                              const __half2* __restrict__ Fxh,
                                              const float* __restrict__ ny2,
                                              float2* __restrict__ G) {
  __shared__ float2 sb[8][264];
  int tid = threadIdx.x, w = tid >> 6, lane = tid & 63;
  float2* s = sb[w];
  int tb = blockIdx.x / 17, oct = blockIdx.x % 17;
  int k = oct * 8 + w;
  bool act = (k <= 128);
  int b = tb & 3;
  if (act) {
    Tw tf = make_tw<false>(lane);
    float2 acc[4];
#pragma unroll
    for (int q = 0; q < 4; ++q) acc[q] = make_float2(0.f, 0.f);
    for (int c = 0; c < Cn; ++c) {
      const __half2* Yp = Yh + ((size_t)(tb * Cn + c) * KF + k) * Hn;
      float2 v[4];
#pragma unroll
      for (int q = 0; q < 4; ++q) v[q] = __half22float2(Yp[lane + (q << 6)]);
      fft256<false>(v, s, lane, tf);
      float nx = sqrtf(ny2[b * Cn + c]);      // t=0 slab == x norms
      float ny = sqrtf(ny2[tb * Cn + c]);
      float sc = 1.0f / ((float)Cn * (nx * ny + 1e-12f));
      const __half2* Fxp = Fxh + ((size_t)(b * Cn + c) * KF + k) * Hn;
#pragma unroll
      for (int q = 0; q < 4; ++q) {
        int rr = lane + (q << 6);
        float2 fy = s[swz(rr)];
        float2 fx = __half22float2(Fxp[rr]);
        acc[q].x += sc * (fx.x * fy.x + fx.y * fy.y);   // fx * conj(fy)
        acc[q].y += sc * (fx.y * fy.x - fx.x * fy.y);
      }
    }
    Tw ti = make_tw<true>(lane);
    fft256<true>(acc, s, lane, ti);         // leaves result in s[swz(j)]
  }
  __syncthreads();
  // cooperative transposed store: 8 consecutive k per j -> 64B granules
  int kk = tid & 7, jj0 = tid >> 3;         // 64 j per pass
  if (oct * 8 + kk <= 128) {
    float2* Gp = G + ((size_t)tb * Hn) * KGP + oct * 8 + kk;
#pragma unroll
    for (int p = 0; p < 4; ++p) {
      int j = jj0 + (p << 6);
      Gp[(size_t)j * KGP] = sb[kk][swz(j)];
    }
  }
}

// ---------------------------------------------------------------------------
// Final pass: block = (b, spatial row i), 5 waves. Wave tp handles t-pair
// (2tp, 2tp+1): Hermitian-extend both spectra, pack A + iB, ONE inverse FFT,
// re/im are the two t's correlations. G reads are fully contiguous now.
// ---------------------------------------------------------------------------
__global__ __launch_bounds__(320) void k_irow(const float2* __restrict__ G,
                                              float* __restrict__ out) {
  __shared__ float2 tile[5][2][132];
  __shared__ float2 sb[5][264];
  __shared__ float rowbuf[Wn * NTn];
  int tid = threadIdx.x, w = tid >> 6, lane = tid & 63;
  Tw ti = make_tw<true>(lane);
  int b = blockIdx.x >> 8, i = blockIdx.x & 255;
  const float scale = 1.0f / ((float)Hn * (float)Wn);
  int t1 = 2 * w, t2 = t1 + 1;
  {
    const float2* Gp1 = G + ((size_t)(t1 * Bn + b) * Hn + i) * KGP;
    for (int k = lane; k < KF; k += 64) tile[w][0][k] = Gp1[k];
    if (t2 < NTn) {
      const float2* Gp2 = G + ((size_t)(t2 * Bn + b) * Hn + i) * KGP;
      for (int k = lane; k < KF; k += 64) tile[w][1][k] = Gp2[k];
    }
  }
  lds_fence();   // tile[w] is wave-private
  float2 v[4];
#pragma unroll
  for (int q = 0; q < 4; ++q) {
    int k = lane + (q << 6);
    float2 a, bb;
    if (k <= 128) a = tile[w][0][k];
    else { float2 z = tile[w][0][256 - k]; a = make_float2(z.x, -z.y); }
    if (t2 < NTn) {
      if (k <= 128) bb = tile[w][1][k];
      else { float2 z = tile[w][1][256 - k]; bb = make_float2(z.x, -z.y); }
    } else bb = make_float2(0.f, 0.f);
    v[q] = make_float2(a.x - bb.y, a.y + bb.x);   // A + i*B
  }
  fft256<true>(v, sb[w], lane, ti);
#pragma unroll
  for (int q = 0; q < 4; ++q) {
    int j = lane + (q << 6);
    float2 r = sb[w][swz(j)];
    rowbuf[j * NTn + t1] = r.x * scale;
    if (t2 < NTn) rowbuf[j * NTn + t2] = r.y * scale;
  }
  __syncthreads();
  float* ob = out + ((size_t)(b * Hn + i) * Wn) * NTn;
  for (int f = tid; f < Wn * NTn; f += 320) ob[f] = rowbuf[f];
}

// ---------------------------------------------------------------------------
extern "C" void kernel_launch(void* const* d_in, const int* in_sizes, int n_in,
                              void* d_out, int out_size, void* d_ws, size_t ws_size,
                              hipStream_t stream) {
  const float* inp = (const float*)d_in[0];
  const float* T   = (const float*)d_in[1];
  float* out = (float*)d_out;
  char* ws = (char*)d_ws;

  size_t off = 0;
  float*   ny2 = (float*)(ws + off);   off += 1024 * sizeof(float);
  __half2* Fxh = (__half2*)(ws + off); off += (size_t)Bn * Cn * KF * Hn * sizeof(__half2);   // 8.5 MB
  float2*  G   = (float2*)(ws + off);  off += (size_t)NTn * Bn * Hn * KGP * sizeof(float2);  // 10.0 MB
  __half2* Yh  = (__half2*)(ws + off); off += (size_t)NTn * Bn * Cn * KF * Hn * sizeof(__half2); // 76 MB
  (void)off; (void)ws_size; (void)in_sizes; (void)n_in; (void)out_size;

  k_zero<<<1, 256, 0, stream>>>(ny2);
  k_yrow<<<NTn * Bn * 4 * 16, 256, 0, stream>>>(inp, T, Yh, ny2);
  k_colfft_fx<<<Bn * Cn * KF / 4, 256, 0, stream>>>(Yh, Fxh);
  k_ycol<<<NTn * Bn * 17, 512, 0, stream>>>(Yh, Fxh, ny2, G);
  k_irow<<<Bn * Hn, 320, 0, stream>>>(G, out);
}

// Round 11
// 213.683 us; speedup vs baseline: 1.0395x; 1.0395x over previous
//
#include <hip/hip_runtime.h>
#include <hip/hip_fp16.h>

#define Bn  4
#define Hn  256
#define Wn  256
#define Cn  16
#define NTn 9
#define HWn (Hn*Wn)
#define KF  129      // W/2 + 1
#define KGP 136      // padded k-row length of G
#define PI_F 3.14159265358979323846f

__device__ __forceinline__ int swz(int i) { return i ^ ((i >> 4) & 15); }

__device__ __forceinline__ void lds_fence() {
  __asm__ volatile("s_waitcnt lgkmcnt(0)" ::: "memory");
}

__device__ __forceinline__ float2 cmul(float2 a, float2 b) {
  return make_float2(a.x*b.x - a.y*b.y, a.x*b.y + a.y*b.x);
}

template<bool INV>
__device__ __forceinline__ void radix4(float2& x0, float2& x1, float2& x2, float2& x3) {
  float2 y0 = make_float2(x0.x + x2.x, x0.y + x2.y);
  float2 y1 = make_float2(x0.x - x2.x, x0.y - x2.y);
  float2 y2 = make_float2(x1.x + x3.x, x1.y + x3.y);
  float2 y3 = make_float2(x1.x - x3.x, x1.y - x3.y);
  x0 = make_float2(y0.x + y2.x, y0.y + y2.y);
  x2 = make_float2(y0.x - y2.x, y0.y - y2.y);
  if (!INV) {
    x1 = make_float2(y1.x + y3.y, y1.y - y3.x);   // y1 - i*y3
    x3 = make_float2(y1.x - y3.y, y1.y + y3.x);   // y1 + i*y3
  } else {
    x1 = make_float2(y1.x - y3.y, y1.y + y3.x);
    x3 = make_float2(y1.x + y3.y, y1.y - y3.x);
  }
}

struct Tw { float2 a1,a2,a3,b1,b2,b3,c1,c2,c3; };

template<bool INV>
__device__ __forceinline__ Tw make_tw(int lane) {
  const float sgn = INV ? 2.0f * PI_F : -2.0f * PI_F;
  Tw t; float sw, cw;
  __sincosf(sgn * (float)lane / 256.0f, &sw, &cw);
  t.a1 = make_float2(cw, sw); t.a2 = cmul(t.a1, t.a1); t.a3 = cmul(t.a2, t.a1);
  __sincosf(sgn * (float)(lane & 15) / 64.0f, &sw, &cw);
  t.b1 = make_float2(cw, sw); t.b2 = cmul(t.b1, t.b1); t.b3 = cmul(t.b2, t.b1);
  __sincosf(sgn * (float)(lane & 3) / 16.0f, &sw, &cw);
  t.c1 = make_float2(cw, sw); t.c2 = cmul(t.c1, t.c1); t.c3 = cmul(t.c2, t.c1);
  return t;
}

// Per-wave FFT-256, radix-4 DIF. Input v[a]=x[lane+64a]; natural-order output
// in scratch row s (read via s[swz(k)]). Wave-private s, no __syncthreads.
template<bool INV>
__device__ __forceinline__ void fft256(float2 v[4], float2* s, int lane, const Tw& t) {
  radix4<INV>(v[0], v[1], v[2], v[3]);
  v[1] = cmul(v[1], t.a1); v[2] = cmul(v[2], t.a2); v[3] = cmul(v[3], t.a3);
  s[swz(lane)]       = v[0];
  s[swz(lane + 64)]  = v[1];
  s[swz(lane + 128)] = v[2];
  s[swz(lane + 192)] = v[3];
  lds_fence();
  { int base = (lane >> 4) * 64 + (lane & 15);
    v[0] = s[swz(base)]; v[1] = s[swz(base + 16)];
    v[2] = s[swz(base + 32)]; v[3] = s[swz(base + 48)]; }
  lds_fence();
  radix4<INV>(v[0], v[1], v[2], v[3]);
  v[1] = cmul(v[1], t.b1); v[2] = cmul(v[2], t.b2); v[3] = cmul(v[3], t.b3);
  { int base = (lane >> 4) * 64 + (lane & 15);
    s[swz(base)]      = v[0];
    s[swz(base + 16)] = v[1];
    s[swz(base + 32)] = v[2];
    s[swz(base + 48)] = v[3]; }
  lds_fence();
  { int base = (lane >> 4) * 64 + ((lane >> 2) & 3) * 16 + (lane & 3);
    v[0] = s[swz(base)]; v[1] = s[swz(base + 4)];
    v[2] = s[swz(base + 8)]; v[3] = s[swz(base + 12)]; }
  lds_fence();
  radix4<INV>(v[0], v[1], v[2], v[3]);
  v[1] = cmul(v[1], t.c1); v[2] = cmul(v[2], t.c2); v[3] = cmul(v[3], t.c3);
  { int base = (lane & ~3) * 4 + (lane & 3);
    s[swz(base)]      = v[0];
    s[swz(base + 4)]  = v[1];
    s[swz(base + 8)]  = v[2];
    s[swz(base + 12)] = v[3]; }
  lds_fence();
  { int base = lane * 4;
    v[0] = s[swz(base)]; v[1] = s[swz(base + 1)];
    v[2] = s[swz(base + 2)]; v[3] = s[swz(base + 3)]; }
  lds_fence();
  radix4<INV>(v[0], v[1], v[2], v[3]);
  int dr = ((lane & 3) << 4) + (((lane >> 2) & 3) << 2) + (lane >> 4);
  s[swz(dr)]       = v[0];
  s[swz(dr + 64)]  = v[1];
  s[swz(dr + 128)] = v[2];
  s[swz(dr + 192)] = v[3];
  lds_fence();
}

// Inline projective warp map (matches reference: fp-contract off, rintf).
__device__ __forceinline__ int warp_id(float a0, float a1, float a2, float a3,
                                       float a4, float a5, float a6, float a7,
                                       int col, int row) {
#pragma clang fp contract(off)
  float x = (float)col, y = (float)row;
  float kk = a6 * x + a7 * y + 1.0f;
  float xf = (a0 * x + a1 * y + a2) / kk;
  float yf = (a3 * x + a4 * y + a5) / kk;
  float xr = rintf(xf), yr = rintf(yf);
  bool valid = (xr >= 0.f) && (xr < 256.f) && (yr >= 0.f) && (yr < 256.f);
  return valid ? ((int)yr * Wn + (int)xr) : -1;
}

// ---------------------------------------------------------------------------
// Row FFT of warped y (t=0 slab == x spectra, identity warp).
// Block = (tb, cg quad, 16-row chunk), R9 ordering (cg in low-middle bits:
// sibling quads temporally adjacent -> L2 line sharing). Wave w is SELF-
// SUFFICIENT: it gathers its own row-pair at columns lane+64q (exactly the
// FFT input positions), so the 4 channels of each float4 feed 4 packed
// real-pair FFTs straight from registers. 4 barriers/block total.
// Norm partials: race-free part[tb][c][chunk] (no atomics, no pre-zero).
// ---------------------------------------------------------------------------
__global__ __launch_bounds__(256) void k_yrow(const float* __restrict__ inp,
                                              const float* __restrict__ T,
                                              __half2* __restrict__ Yh,
                                              float* __restrict__ part) {
  __shared__ float2  sb[4][264];
  __shared__ __half2 specbuf[4][8][132];
  __shared__ float4  redw[4];
  int tid = threadIdx.x, w = tid >> 6, lane = tid & 63;
  Tw t = make_tw<false>(lane);
  int chunk = blockIdx.x & 15, cg = (blockIdx.x >> 4) & 3, tb = blockIdx.x >> 6;
  int b = tb & 3, tt = tb >> 2;
  int i0 = chunk << 4;
  const float4* ib = (const float4*)(inp + (size_t)b * HWn * Cn);
  float a0, a1, a2, a3, a4, a5, a6, a7;
  { const float* a = T + tt * 8;
    a0=a[0]; a1=a[1]; a2=a[2]; a3=a[3]; a4=a[4]; a5=a[5]; a6=a[6]; a7=a[7]; }
  float4 nyacc = make_float4(0.f, 0.f, 0.f, 0.f);
  for (int h = 0; h < 2; ++h) {
    if (h) __syncthreads();                  // specbuf reuse
    int r0 = i0 + h * 8 + 2 * w;             // wave's row pair: r0, r0+1
    float4 g0[4], g1[4];
#pragma unroll
    for (int q = 0; q < 4; ++q) {
      int col = lane + (q << 6);
      int id0 = warp_id(a0,a1,a2,a3,a4,a5,a6,a7, col, r0);
      int id1 = warp_id(a0,a1,a2,a3,a4,a5,a6,a7, col, r0 + 1);
      g0[q] = (id0 >= 0) ? ib[(size_t)id0 * 4 + cg] : make_float4(0.f,0.f,0.f,0.f);
      g1[q] = (id1 >= 0) ? ib[(size_t)id1 * 4 + cg] : make_float4(0.f,0.f,0.f,0.f);
      nyacc.x += g0[q].x*g0[q].x + g1[q].x*g1[q].x;
      nyacc.y += g0[q].y*g0[q].y + g1[q].y*g1[q].y;
      nyacc.z += g0[q].z*g0[q].z + g1[q].z*g1[q].z;
      nyacc.w += g0[q].w*g0[q].w + g1[q].w*g1[q].w;
    }
    int lr0 = 2 * w, lr1 = lr0 + 1;
#pragma unroll
    for (int cc = 0; cc < 4; ++cc) {
      float2 v[4];
#pragma unroll
      for (int q = 0; q < 4; ++q) {
        float e0 = (cc == 0) ? g0[q].x : (cc == 1) ? g0[q].y : (cc == 2) ? g0[q].z : g0[q].w;
        float e1 = (cc == 0) ? g1[q].x : (cc == 1) ? g1[q].y : (cc == 2) ? g1[q].z : g1[q].w;
        v[q] = make_float2(e0, e1);
      }
      fft256<false>(v, sb[w], lane, t);
#pragma unroll
      for (int q = 0; q < 2; ++q) {
        int k = lane + (q << 6);
        float2 Z  = sb[w][swz(k)];
        float2 Zc = sb[w][swz((256 - k) & 255)];
        float2 Fa = make_float2(0.5f * (Z.x + Zc.x), 0.5f * (Z.y - Zc.y));
        float2 Fb = make_float2(0.5f * (Z.y + Zc.y), 0.5f * (Zc.x - Z.x));
        specbuf[cc][lr0][k] = __float22half2_rn(Fa);
        specbuf[cc][lr1][k] = __float22half2_rn(Fb);
      }
      if (lane == 0) {
        float2 Z = sb[w][swz(128)];
        specbuf[cc][lr0][128] = __float22half2_rn(make_float2(Z.x, 0.f));
        specbuf[cc][lr1][128] = __float22half2_rn(make_float2(Z.y, 0.f));
      }
    }
    __syncthreads();
    // flush 8 rows, 32B granules (8 consecutive i per store group)
    int ii = tid & 7, kq = tid >> 3;
#pragma unroll
    for (int p = 0; p < 5; ++p) {
      int k = p * 32 + kq;
      if (k <= 128) {
#pragma unroll
        for (int cc = 0; cc < 4; ++cc)
          Yh[((size_t)(tb * Cn + cg * 4 + cc) * KF + k) * Hn + i0 + h * 8 + ii] = specbuf[cc][ii][k];
      }
    }
  }
#pragma unroll
  for (int o = 32; o > 0; o >>= 1) {
    nyacc.x += __shfl_down(nyacc.x, o, 64);
    nyacc.y += __shfl_down(nyacc.y, o, 64);
    nyacc.z += __shfl_down(nyacc.z, o, 64);
    nyacc.w += __shfl_down(nyacc.w, o, 64);
  }
  if (lane == 0) redw[w] = nyacc;
  __syncthreads();
  if (tid == 0) {
    float4 s = make_float4(redw[0].x + redw[1].x + redw[2].x + redw[3].x,
                           redw[0].y + redw[1].y + redw[2].y + redw[3].y,
                           redw[0].z + redw[1].z + redw[2].z + redw[3].z,
                           redw[0].w + redw[1].w + redw[2].w + redw[3].w);
    part[((size_t)tb * Cn + cg * 4 + 0) * 16 + chunk] = s.x;
    part[((size_t)tb * Cn + cg * 4 + 1) * 16 + chunk] = s.y;
    part[((size_t)tb * Cn + cg * 4 + 2) * 16 + chunk] = s.z;
    part[((size_t)tb * Cn + cg * 4 + 3) * 16 + chunk] = s.w;
  }
}

// ---------------------------------------------------------------------------
// Column FFT of x spectra: reads t=0 slab of Yh (contiguous), writes Fxh
// (contiguous). Wave per item, no barriers.
// ---------------------------------------------------------------------------
__global__ void k_colfft_fx(const __half2* __restrict__ Yh, __half2* __restrict__ Fxh) {
  __shared__ float2 sb[4][264];
  int w = threadIdx.x >> 6, lane = threadIdx.x & 63;
  Tw t = make_tw<false>(lane);
  int item = blockIdx.x * 4 + w;            // (b*16+c)*KF + k
  const __half2* Sp = Yh + (size_t)item * Hn;
  float2 v[4];
#pragma unroll
  for (int q = 0; q < 4; ++q) v[q] = __half22float2(Sp[lane + (q << 6)]);
  fft256<false>(v, sb[w], lane, t);
  __half2* Op = Fxh + (size_t)item * Hn;
#pragma unroll
  for (int q = 0; q < 4; ++q) {
    int j = lane + (q << 6);
    Op[j] = __float22half2_rn(sb[w][swz(j)]);
  }
}

// ---------------------------------------------------------------------------
// Block = (tb, k-octet): 8 waves, wave w owns k = oct*8+w. sc[16] precomputed
// from norm partials (one barrier), then barrier-free per-wave work: column
// FFT over 16 channels + Fx*conj(Fy)*sc accum + fused inverse FFT. Final
// barrier + cooperative 64B-granule transposed store into G[tb][j][k].
// ---------------------------------------------------------------------------
__global__ __launch_bounds__(512) void k_ycol(const __half2* __restrict__ Yh,
                                              const __half2* __restrict__ Fxh,
                                              const float* __restrict__ part,
                                              float2* __restrict__ G) {
  __shared__ float2 sb[8][264];
  __shared__ float scs[16];
  int tid = threadIdx.x, w = tid >> 6, lane = tid & 63;
  float2* s = sb[w];
  int tb = blockIdx.x / 17, oct = blockIdx.x % 17;
  int b = tb & 3;
  if (tid < 16) {
    float sx = 0.f, sy = 0.f;
#pragma unroll
    for (int ch = 0; ch < 16; ++ch) {
      sx += part[((size_t)b  * Cn + tid) * 16 + ch];   // t=0 slab == x norms
      sy += part[((size_t)tb * Cn + tid) * 16 + ch];
    }
    scs[tid] = 1.0f / ((float)Cn * (sqrtf(sx) * sqrtf(sy) + 1e-12f));
  }
  __syncthreads();
  int k = oct * 8 + w;
  bool act = (k <= 128);
  if (act) {
    Tw tf = make_tw<false>(lane);
    float2 acc[4];
#pragma unroll
    for (int q = 0; q < 4; ++q) acc[q] = make_float2(0.f, 0.f);
    for (int c = 0; c < Cn; ++c) {
      const __half2* Yp = Yh + ((size_t)(tb * Cn + c) * KF + k) * Hn;
      float2 v[4];
#pragma unroll
      for (int q = 0; q < 4; ++q) v[q] = __half22float2(Yp[lane + (q << 6)]);
      fft256<false>(v, s, lane, tf);
      float sc = scs[c];
      const __half2* Fxp = Fxh + ((size_t)(b * Cn + c) * KF + k) * Hn;
#pragma unroll
      for (int q = 0; q < 4; ++q) {
        int rr = lane + (q << 6);
        float2 fy = s[swz(rr)];
        float2 fx = __half22float2(Fxp[rr]);
        acc[q].x += sc * (fx.x * fy.x + fx.y * fy.y);   // fx * conj(fy)
        acc[q].y += sc * (fx.y * fy.x - fx.x * fy.y);
      }
    }
    Tw ti = make_tw<true>(lane);
    fft256<true>(acc, s, lane, ti);         // result in s[swz(j)]
  }
  __syncthreads();
  // cooperative transposed store: 8 consecutive k per j -> 64B granules
  int kk = tid & 7, jj0 = tid >> 3;
  if (oct * 8 + kk <= 128) {
    float2* Gp = G + ((size_t)tb * Hn) * KGP + oct * 8 + kk;
#pragma unroll
    for (int p = 0; p < 4; ++p) {
      int j = jj0 + (p << 6);
      Gp[(size_t)j * KGP] = sb[kk][swz(j)];
    }
  }
}

// ---------------------------------------------------------------------------
// Final pass: block = (b, spatial row i), 5 waves. Wave tp handles t-pair
// (2tp, 2tp+1): Hermitian-extend both spectra, pack A + iB, ONE inverse FFT,
// re/im are the two t's correlations. G reads fully contiguous.
// ---------------------------------------------------------------------------
__global__ __launch_bounds__(320) void k_irow(const float2* __restrict__ G,
                                              float* __restrict__ out) {
  __shared__ float2 tile[5][2][132];
  __shared__ float2 sb[5][264];
  __shared__ float rowbuf[Wn * NTn];
  int tid = threadIdx.x, w = tid >> 6, lane = tid & 63;
  Tw ti = make_tw<true>(lane);
  int b = blockIdx.x >> 8, i = blockIdx.x & 255;
  const float scale = 1.0f / ((float)Hn * (float)Wn);
  int t1 = 2 * w, t2 = t1 + 1;
  {
    const float2* Gp1 = G + ((size_t)(t1 * Bn + b) * Hn + i) * KGP;
    for (int k = lane; k < KF; k += 64) tile[w][0][k] = Gp1[k];
    if (t2 < NTn) {
      const float2* Gp2 = G + ((size_t)(t2 * Bn + b) * Hn + i) * KGP;
      for (int k = lane; k < KF; k += 64) tile[w][1][k] = Gp2[k];
    }
  }
  lds_fence();   // tile[w] is wave-private
  float2 v[4];
#pragma unroll
  for (int q = 0; q < 4; ++q) {
    int k = lane + (q << 6);
    float2 a, bb;
    if (k <= 128) a = tile[w][0][k];
    else { float2 z = tile[w][0][256 - k]; a = make_float2(z.x, -z.y); }
    if (t2 < NTn) {
      if (k <= 128) bb = tile[w][1][k];
      else { float2 z = tile[w][1][256 - k]; bb = make_float2(z.x, -z.y); }
    } else bb = make_float2(0.f, 0.f);
    v[q] = make_float2(a.x - bb.y, a.y + bb.x);   // A + i*B
  }
  fft256<true>(v, sb[w], lane, ti);
#pragma unroll
  for (int q = 0; q < 4; ++q) {
    int j = lane + (q << 6);
    float2 r = sb[w][swz(j)];
    rowbuf[j * NTn + t1] = r.x * scale;
    if (t2 < NTn) rowbuf[j * NTn + t2] = r.y * scale;
  }
  __syncthreads();
  float* ob = out + ((size_t)(b * Hn + i) * Wn) * NTn;
  for (int f = tid; f < Wn * NTn; f += 320) ob[f] = rowbuf[f];
}

// ---------------------------------------------------------------------------
extern "C" void kernel_launch(void* const* d_in, const int* in_sizes, int n_in,
                              void* d_out, int out_size, void* d_ws, size_t ws_size,
                              hipStream_t stream) {
  const float* inp = (const float*)d_in[0];
  const float* T   = (const float*)d_in[1];
  float* out = (float*)d_out;
  char* ws = (char*)d_ws;

  size_t off = 0;
  float*   part = (float*)(ws + off);  off += (size_t)NTn * Bn * Cn * 16 * sizeof(float);   // 36 KB
  __half2* Fxh = (__half2*)(ws + off); off += (size_t)Bn * Cn * KF * Hn * sizeof(__half2);  // 8.5 MB
  float2*  G   = (float2*)(ws + off);  off += (size_t)NTn * Bn * Hn * KGP * sizeof(float2); // 10.0 MB
  __half2* Yh  = (__half2*)(ws + off); off += (size_t)NTn * Bn * Cn * KF * Hn * sizeof(__half2); // 76 MB
  (void)off; (void)ws_size; (void)in_sizes; (void)n_in; (void)out_size;

  k_yrow<<<NTn * Bn * 64, 256, 0, stream>>>(inp, T, Yh, part);
  k_colfft_fx<<<Bn * Cn * KF / 4, 256, 0, stream>>>(Yh, Fxh);
  k_ycol<<<NTn * Bn * 17, 512, 0, stream>>>(Yh, Fxh, part, G);
  k_irow<<<Bn * Hn, 320, 0, stream>>>(G, out);
}

// Round 12
// 193.041 us; speedup vs baseline: 1.1507x; 1.1069x over previous
//
#include <hip/hip_runtime.h>
#include <hip/hip_fp16.h>

#define Bn  4
#define Hn  256
#define Wn  256
#define Cn  16
#define NTn 9
#define HWn (Hn*Wn)
#define KF  129      // W/2 + 1
#define KGP 136      // padded k-row length of G
#define SRL 266      // scratch row length (bank-stagger padded)
#define PI_F 3.14159265358979323846f

__device__ __forceinline__ int swz(int i) { return i ^ ((i >> 4) & 15); }

__device__ __forceinline__ void lds_fence() {
  __asm__ volatile("s_waitcnt lgkmcnt(0)" ::: "memory");
}

__device__ __forceinline__ float2 cmul(float2 a, float2 b) {
  return make_float2(a.x*b.x - a.y*b.y, a.x*b.y + a.y*b.x);
}

template<bool INV>
__device__ __forceinline__ void radix4(float2& x0, float2& x1, float2& x2, float2& x3) {
  float2 y0 = make_float2(x0.x + x2.x, x0.y + x2.y);
  float2 y1 = make_float2(x0.x - x2.x, x0.y - x2.y);
  float2 y2 = make_float2(x1.x + x3.x, x1.y + x3.y);
  float2 y3 = make_float2(x1.x - x3.x, x1.y - x3.y);
  x0 = make_float2(y0.x + y2.x, y0.y + y2.y);
  x2 = make_float2(y0.x - y2.x, y0.y - y2.y);
  if (!INV) {
    x1 = make_float2(y1.x + y3.y, y1.y - y3.x);   // y1 - i*y3
    x3 = make_float2(y1.x - y3.y, y1.y + y3.x);   // y1 + i*y3
  } else {
    x1 = make_float2(y1.x - y3.y, y1.y + y3.x);
    x3 = make_float2(y1.x + y3.y, y1.y - y3.x);
  }
}

struct Tw { float2 a1,a2,a3,b1,b2,b3,c1,c2,c3; };

template<bool INV>
__device__ __forceinline__ Tw make_tw(int lane) {
  const float sgn = INV ? 2.0f * PI_F : -2.0f * PI_F;
  Tw t; float sw, cw;
  __sincosf(sgn * (float)lane / 256.0f, &sw, &cw);
  t.a1 = make_float2(cw, sw); t.a2 = cmul(t.a1, t.a1); t.a3 = cmul(t.a2, t.a1);
  __sincosf(sgn * (float)(lane & 15) / 64.0f, &sw, &cw);
  t.b1 = make_float2(cw, sw); t.b2 = cmul(t.b1, t.b1); t.b3 = cmul(t.b2, t.b1);
  __sincosf(sgn * (float)(lane & 3) / 16.0f, &sw, &cw);
  t.c1 = make_float2(cw, sw); t.c2 = cmul(t.c1, t.c1); t.c3 = cmul(t.c2, t.c1);
  return t;
}

// ---------------------------------------------------------------------------
// NF per-wave FFT-256s in LOCKSTEP: all NF FFTs issue their DS writes before
// each fence, so the exchange-drain latency is amortized NF-fold.
// Input v[f][a] = x_f[lane+64a]; output natural order in s[f][swz(k)].
// s = NF wave-private scratch rows. No __syncthreads.
// ---------------------------------------------------------------------------
template<bool INV, int NF>
__device__ __forceinline__ void fft256_n(float2 (*v)[4], float2 (*s)[SRL],
                                         int lane, const Tw& t) {
#pragma unroll
  for (int f = 0; f < NF; ++f) {
    radix4<INV>(v[f][0], v[f][1], v[f][2], v[f][3]);
    v[f][1] = cmul(v[f][1], t.a1); v[f][2] = cmul(v[f][2], t.a2); v[f][3] = cmul(v[f][3], t.a3);
#pragma unroll
    for (int a = 0; a < 4; ++a) s[f][swz(lane + (a << 6))] = v[f][a];
  }
  lds_fence();
  { int base = (lane >> 4) * 64 + (lane & 15);
#pragma unroll
    for (int f = 0; f < NF; ++f)
#pragma unroll
      for (int a = 0; a < 4; ++a) v[f][a] = s[f][swz(base + (a << 4))];
  }
  lds_fence();
#pragma unroll
  for (int f = 0; f < NF; ++f) {
    radix4<INV>(v[f][0], v[f][1], v[f][2], v[f][3]);
    v[f][1] = cmul(v[f][1], t.b1); v[f][2] = cmul(v[f][2], t.b2); v[f][3] = cmul(v[f][3], t.b3);
    int base = (lane >> 4) * 64 + (lane & 15);
#pragma unroll
    for (int a = 0; a < 4; ++a) s[f][swz(base + (a << 4))] = v[f][a];
  }
  lds_fence();
  { int base = (lane >> 4) * 64 + ((lane >> 2) & 3) * 16 + (lane & 3);
#pragma unroll
    for (int f = 0; f < NF; ++f)
#pragma unroll
      for (int a = 0; a < 4; ++a) v[f][a] = s[f][swz(base + (a << 2))];
  }
  lds_fence();
#pragma unroll
  for (int f = 0; f < NF; ++f) {
    radix4<INV>(v[f][0], v[f][1], v[f][2], v[f][3]);
    v[f][1] = cmul(v[f][1], t.c1); v[f][2] = cmul(v[f][2], t.c2); v[f][3] = cmul(v[f][3], t.c3);
    int base = (lane & ~3) * 4 + (lane & 3);
#pragma unroll
    for (int a = 0; a < 4; ++a) s[f][swz(base + (a << 2))] = v[f][a];
  }
  lds_fence();
  { int base = lane * 4;
#pragma unroll
    for (int f = 0; f < NF; ++f)
#pragma unroll
      for (int a = 0; a < 4; ++a) v[f][a] = s[f][swz(base + a)];
  }
  lds_fence();
  int dr = ((lane & 3) << 4) + (((lane >> 2) & 3) << 2) + (lane >> 4);
#pragma unroll
  for (int f = 0; f < NF; ++f) {
    radix4<INV>(v[f][0], v[f][1], v[f][2], v[f][3]);
#pragma unroll
    for (int a = 0; a < 4; ++a) s[f][swz(dr + (a << 6))] = v[f][a];
  }
  lds_fence();
}

// Inline projective warp map (matches reference: fp-contract off, rintf).
__device__ __forceinline__ int warp_id(float a0, float a1, float a2, float a3,
                                       float a4, float a5, float a6, float a7,
                                       int col, int row) {
#pragma clang fp contract(off)
  float x = (float)col, y = (float)row;
  float kk = a6 * x + a7 * y + 1.0f;
  float xf = (a0 * x + a1 * y + a2) / kk;
  float yf = (a3 * x + a4 * y + a5) / kk;
  float xr = rintf(xf), yr = rintf(yf);
  bool valid = (xr >= 0.f) && (xr < 256.f) && (yr >= 0.f) && (yr < 256.f);
  return valid ? ((int)yr * Wn + (int)xr) : -1;
}

// ---------------------------------------------------------------------------
// Row FFT of warped y (t=0 slab == x spectra). Block = (tb, cg quad, 16-row
// chunk). Wave w gathers its own row-pair at FFT input positions; the 4
// channels of each float4 feed a q4-batched real-pair FFT. After one barrier,
// the block's 16 scratch rows hold 8 rows x 4ch of spectra: the store phase
// Hermitian-unpacks directly from scratch (no staging buffer) with 32B
// granules. Race-free norm partials.
// ---------------------------------------------------------------------------
__global__ __launch_bounds__(256) void k_yrow(const float* __restrict__ inp,
                                              const float* __restrict__ T,
                                              __half2* __restrict__ Yh,
                                              float* __restrict__ part) {
  __shared__ float2 sb[4][4][SRL];
  __shared__ float4 redw[4];
  int tid = threadIdx.x, w = tid >> 6, lane = tid & 63;
  Tw t = make_tw<false>(lane);
  int chunk = blockIdx.x & 15, cg = (blockIdx.x >> 4) & 3, tb = blockIdx.x >> 6;
  int b = tb & 3, tt = tb >> 2;
  int i0 = chunk << 4;
  const float4* ib = (const float4*)(inp + (size_t)b * HWn * Cn);
  float a0, a1, a2, a3, a4, a5, a6, a7;
  { const float* a = T + tt * 8;
    a0=a[0]; a1=a[1]; a2=a[2]; a3=a[3]; a4=a[4]; a5=a[5]; a6=a[6]; a7=a[7]; }
  float4 nyacc = make_float4(0.f, 0.f, 0.f, 0.f);
  for (int h = 0; h < 2; ++h) {
    if (h) __syncthreads();                  // scratch reuse across halves
    int r0 = i0 + h * 8 + 2 * w;             // wave's row pair
    float4 g0[4], g1[4];
#pragma unroll
    for (int q = 0; q < 4; ++q) {
      int col = lane + (q << 6);
      int id0 = warp_id(a0,a1,a2,a3,a4,a5,a6,a7, col, r0);
      int id1 = warp_id(a0,a1,a2,a3,a4,a5,a6,a7, col, r0 + 1);
      g0[q] = (id0 >= 0) ? ib[(size_t)id0 * 4 + cg] : make_float4(0.f,0.f,0.f,0.f);
      g1[q] = (id1 >= 0) ? ib[(size_t)id1 * 4 + cg] : make_float4(0.f,0.f,0.f,0.f);
      nyacc.x += g0[q].x*g0[q].x + g1[q].x*g1[q].x;
      nyacc.y += g0[q].y*g0[q].y + g1[q].y*g1[q].y;
      nyacc.z += g0[q].z*g0[q].z + g1[q].z*g1[q].z;
      nyacc.w += g0[q].w*g0[q].w + g1[q].w*g1[q].w;
    }
    float2 v[4][4];
#pragma unroll
    for (int q = 0; q < 4; ++q) {
      v[0][q] = make_float2(g0[q].x, g1[q].x);
      v[1][q] = make_float2(g0[q].y, g1[q].y);
      v[2][q] = make_float2(g0[q].z, g1[q].z);
      v[3][q] = make_float2(g0[q].w, g1[q].w);
    }
    fft256_n<false, 4>(v, sb[w], lane, t);
    __syncthreads();
    // store phase: thread (ii=row 0..7, kq) unpacks Fa/Fb from scratch
    int ii = tid & 7, kq = tid >> 3;
    int w2 = ii >> 1, odd = ii & 1;
#pragma unroll
    for (int p = 0; p < 5; ++p) {
      int k = p * 32 + kq;
      if (k <= 128) {
        int kc = (256 - k) & 255;
#pragma unroll
        for (int cc = 0; cc < 4; ++cc) {
          float2 Z  = sb[w2][cc][swz(k)];
          float2 Zc = sb[w2][cc][swz(kc)];
          float2 F = odd ? make_float2(0.5f * (Z.y + Zc.y), 0.5f * (Zc.x - Z.x))
                         : make_float2(0.5f * (Z.x + Zc.x), 0.5f * (Z.y - Zc.y));
          Yh[((size_t)(tb * Cn + cg * 4 + cc) * KF + k) * Hn + i0 + h * 8 + ii] =
              __float22half2_rn(F);
        }
      }
    }
  }
#pragma unroll
  for (int o = 32; o > 0; o >>= 1) {
    nyacc.x += __shfl_down(nyacc.x, o, 64);
    nyacc.y += __shfl_down(nyacc.y, o, 64);
    nyacc.z += __shfl_down(nyacc.z, o, 64);
    nyacc.w += __shfl_down(nyacc.w, o, 64);
  }
  if (lane == 0) redw[w] = nyacc;
  __syncthreads();
  if (tid == 0) {
    float4 s = make_float4(redw[0].x + redw[1].x + redw[2].x + redw[3].x,
                           redw[0].y + redw[1].y + redw[2].y + redw[3].y,
                           redw[0].z + redw[1].z + redw[2].z + redw[3].z,
                           redw[0].w + redw[1].w + redw[2].w + redw[3].w);
    part[((size_t)tb * Cn + cg * 4 + 0) * 16 + chunk] = s.x;
    part[((size_t)tb * Cn + cg * 4 + 1) * 16 + chunk] = s.y;
    part[((size_t)tb * Cn + cg * 4 + 2) * 16 + chunk] = s.z;
    part[((size_t)tb * Cn + cg * 4 + 3) * 16 + chunk] = s.w;
  }
}

// ---------------------------------------------------------------------------
// Column FFT of x spectra, q4-batched: each wave does 4 consecutive items.
// ---------------------------------------------------------------------------
__global__ __launch_bounds__(256) void k_colfft_fx(const __half2* __restrict__ Yh,
                                                   __half2* __restrict__ Fxh) {
  __shared__ float2 sb[4][4][SRL];
  int tid = threadIdx.x, w = tid >> 6, lane = tid & 63;
  Tw t = make_tw<false>(lane);
  int base_item = blockIdx.x * 16 + w * 4;   // (b*16+c)*KF + k
  float2 v[4][4];
#pragma unroll
  for (int f = 0; f < 4; ++f) {
    const __half2* Sp = Yh + (size_t)(base_item + f) * Hn;
#pragma unroll
    for (int q = 0; q < 4; ++q) v[f][q] = __half22float2(Sp[lane + (q << 6)]);
  }
  fft256_n<false, 4>(v, sb[w], lane, t);
#pragma unroll
  for (int f = 0; f < 4; ++f) {
    __half2* Op = Fxh + (size_t)(base_item + f) * Hn;
#pragma unroll
    for (int q = 0; q < 4; ++q) {
      int j = lane + (q << 6);
      Op[j] = __float22half2_rn(sb[w][f][swz(j)]);
    }
  }
}

// ---------------------------------------------------------------------------
// Block = (tb, k-quartet): 4 waves, wave w owns k = quart*4+w. Channels
// processed in x2-batched pairs (shared fences). Fused inverse FFT, then one
// barrier + cooperative 32B-granule transposed store into G[tb][j][k].
// ---------------------------------------------------------------------------
__global__ __launch_bounds__(256) void k_ycol(const __half2* __restrict__ Yh,
                                              const __half2* __restrict__ Fxh,
                                              const float* __restrict__ part,
                                              float2* __restrict__ G) {
  __shared__ float2 sb[4][2][SRL];
  __shared__ float scs[16];
  int tid = threadIdx.x, w = tid >> 6, lane = tid & 63;
  int tb = blockIdx.x / 33, quart = blockIdx.x % 33;
  int b = tb & 3;
  if (tid < 16) {
    float sx = 0.f, sy = 0.f;
#pragma unroll
    for (int ch = 0; ch < 16; ++ch) {
      sx += part[((size_t)b  * Cn + tid) * 16 + ch];   // t=0 slab == x norms
      sy += part[((size_t)tb * Cn + tid) * 16 + ch];
    }
    scs[tid] = 1.0f / ((float)Cn * (sqrtf(sx) * sqrtf(sy) + 1e-12f));
  }
  __syncthreads();
  int k = quart * 4 + w;
  bool act = (k <= 128);
  if (act) {
    Tw tf = make_tw<false>(lane);
    float2 acc[4];
#pragma unroll
    for (int q = 0; q < 4; ++q) acc[q] = make_float2(0.f, 0.f);
    for (int c = 0; c < Cn; c += 2) {
      float2 v2[2][4];
#pragma unroll
      for (int e = 0; e < 2; ++e) {
        const __half2* Yp = Yh + ((size_t)(tb * Cn + c + e) * KF + k) * Hn;
#pragma unroll
        for (int q = 0; q < 4; ++q) v2[e][q] = __half22float2(Yp[lane + (q << 6)]);
      }
      fft256_n<false, 2>(v2, sb[w], lane, tf);
#pragma unroll
      for (int e = 0; e < 2; ++e) {
        float sc = scs[c + e];
        const __half2* Fxp = Fxh + ((size_t)(b * Cn + c + e) * KF + k) * Hn;
#pragma unroll
        for (int q = 0; q < 4; ++q) {
          int rr = lane + (q << 6);
          float2 fy = sb[w][e][swz(rr)];
          float2 fx = __half22float2(Fxp[rr]);
          acc[q].x += sc * (fx.x * fy.x + fx.y * fy.y);   // fx * conj(fy)
          acc[q].y += sc * (fx.y * fy.x - fx.x * fy.y);
        }
      }
    }
    Tw ti = make_tw<true>(lane);
    fft256_n<true, 1>(reinterpret_cast<float2(*)[4]>(acc), sb[w], lane, ti);
  }
  __syncthreads();
  // transposed store: 4 consecutive k per j -> 32B granules
  int kk = tid & 3, jj0 = tid >> 2;
  if (quart * 4 + kk <= 128) {
    float2* Gp = G + ((size_t)tb * Hn) * KGP + quart * 4 + kk;
#pragma unroll
    for (int p = 0; p < 4; ++p) {
      int j = jj0 + (p << 6);
      Gp[(size_t)j * KGP] = sb[kk][0][swz(j)];
    }
  }
}

// ---------------------------------------------------------------------------
// Final pass: block = (b, spatial row i), 5 waves. Wave tp handles t-pair
// (2tp, 2tp+1): Hermitian-extend both spectra, pack A + iB, ONE inverse FFT,
// re/im are the two t's correlations. G reads fully contiguous.
// ---------------------------------------------------------------------------
__global__ __launch_bounds__(320) void k_irow(const float2* __restrict__ G,
                                              float* __restrict__ out) {
  __shared__ float2 tile[5][2][132];
  __shared__ float2 sb[5][SRL];
  __shared__ float rowbuf[Wn * NTn];
  int tid = threadIdx.x, w = tid >> 6, lane = tid & 63;
  Tw ti = make_tw<true>(lane);
  int b = blockIdx.x >> 8, i = blockIdx.x & 255;
  const float scale = 1.0f / ((float)Hn * (float)Wn);
  int t1 = 2 * w, t2 = t1 + 1;
  {
    const float2* Gp1 = G + ((size_t)(t1 * Bn + b) * Hn + i) * KGP;
    for (int k = lane; k < KF; k += 64) tile[w][0][k] = Gp1[k];
    if (t2 < NTn) {
      const float2* Gp2 = G + ((size_t)(t2 * Bn + b) * Hn + i) * KGP;
      for (int k = lane; k < KF; k += 64) tile[w][1][k] = Gp2[k];
    }
  }
  lds_fence();   // tile[w] is wave-private
  float2 v[1][4];
#pragma unroll
  for (int q = 0; q < 4; ++q) {
    int k = lane + (q << 6);
    float2 a, bb;
    if (k <= 128) a = tile[w][0][k];
    else { float2 z = tile[w][0][256 - k]; a = make_float2(z.x, -z.y); }
    if (t2 < NTn) {
      if (k <= 128) bb = tile[w][1][k];
      else { float2 z = tile[w][1][256 - k]; bb = make_float2(z.x, -z.y); }
    } else bb = make_float2(0.f, 0.f);
    v[0][q] = make_float2(a.x - bb.y, a.y + bb.x);   // A + i*B
  }
  fft256_n<true, 1>(v, reinterpret_cast<float2(*)[SRL]>(sb[w]), lane, ti);
#pragma unroll
  for (int q = 0; q < 4; ++q) {
    int j = lane + (q << 6);
    float2 r = sb[w][swz(j)];
    rowbuf[j * NTn + t1] = r.x * scale;
    if (t2 < NTn) rowbuf[j * NTn + t2] = r.y * scale;
  }
  __syncthreads();
  float* ob = out + ((size_t)(b * Hn + i) * Wn) * NTn;
  for (int f = tid; f < Wn * NTn; f += 320) ob[f] = rowbuf[f];
}

// ---------------------------------------------------------------------------
extern "C" void kernel_launch(void* const* d_in, const int* in_sizes, int n_in,
                              void* d_out, int out_size, void* d_ws, size_t ws_size,
                              hipStream_t stream) {
  const float* inp = (const float*)d_in[0];
  const float* T   = (const float*)d_in[1];
  float* out = (float*)d_out;
  char* ws = (char*)d_ws;

  size_t off = 0;
  float*   part = (float*)(ws + off);  off += (size_t)NTn * Bn * Cn * 16 * sizeof(float);   // 36 KB
  __half2* Fxh = (__half2*)(ws + off); off += (size_t)Bn * Cn * KF * Hn * sizeof(__half2);  // 8.5 MB
  float2*  G   = (float2*)(ws + off);  off += (size_t)NTn * Bn * Hn * KGP * sizeof(float2); // 10.0 MB
  __half2* Yh  = (__half2*)(ws + off); off += (size_t)NTn * Bn * Cn * KF * Hn * sizeof(__half2); // 76 MB
  (void)off; (void)ws_size; (void)in_sizes; (void)n_in; (void)out_size;

  k_yrow<<<NTn * Bn * 64, 256, 0, stream>>>(inp, T, Yh, part);
  k_colfft_fx<<<Bn * Cn * KF / 4 / 4, 256, 0, stream>>>(Yh, Fxh);   // 516 blocks
  k_ycol<<<NTn * Bn * 33, 256, 0, stream>>>(Yh, Fxh, part, G);
  k_irow<<<Bn * Hn, 320, 0, stream>>>(G, out);
}